// Round 7
// baseline (633.072 us; speedup 1.0000x reference)
//
#include <hip/hip_runtime.h>

typedef __attribute__((ext_vector_type(8))) short s16x8;
typedef __attribute__((ext_vector_type(4))) float f32x4;

// ---------------- bf16 helpers (RNE) ----------------
__device__ __forceinline__ unsigned short f2bf(float x) {
  unsigned u = __float_as_uint(x);
  u = (u + 0x7fffu + ((u >> 16) & 1u)) >> 16;
  return (unsigned short)u;
}
__device__ __forceinline__ unsigned cvt_pk_bf16(float a, float b) {
  unsigned r;
  asm("v_cvt_pk_bf16_f32 %0, %1, %2" : "=v"(r) : "v"(a), "v"(b));
  return r;
}
__device__ __forceinline__ float bflo(unsigned v) { return __uint_as_float(v << 16); }
__device__ __forceinline__ float bfhi(unsigned v) { return __uint_as_float(v & 0xffff0000u); }

// lgkm-only barrier: orders LDS across the block WITHOUT draining vmcnt --
// in-flight global B prefetches survive across it.
__device__ __forceinline__ void lgkm_barrier() {
  asm volatile("s_waitcnt lgkmcnt(0)" ::: "memory");
  __builtin_amdgcn_s_barrier();
  asm volatile("" ::: "memory");
}

// ---------------- ws layout (ushort units) ----------------
#define FEAT_OFF 0
#define W0F_OFF  2097152
#define W1F_OFF  (W0F_OFF + 24576)
#define W2F_OFF  (W1F_OFF + 65536)
#define W3P_OFF  (W2F_OFF + 65536)
#define WS_TOTAL (W3P_OFF + 512)

// H columns are stored permuted: position k' holds logical col
//   col_log(k') = (k'&0xC0) | ((k'&3)<<4) | ((k'>>2)&15)
__device__ __forceinline__ int col_log(int kp) {
  return (kp & 0xC0) | ((kp & 3) << 4) | ((kp >> 2) & 15);
}
// LDS h tiles additionally use an address XOR swizzle (T2): short index
//   idx(row,col) = row*256 + (col ^ ((row&7)<<3))
// bijective, preserves 16B/8B alignment (col always mult of 4), balances banks.
__device__ __forceinline__ int hswz(int row, int col) {
  return row * 256 + (col ^ ((row & 7) << 3));
}

__global__ void liif_prep(const float* __restrict__ inp,
                          const float* __restrict__ W0,
                          const float* __restrict__ W1,
                          const float* __restrict__ W2,
                          const float* __restrict__ W3,
                          unsigned short* __restrict__ ws) {
  int tid = blockIdx.x * 256 + threadIdx.x;
  if (tid < 2097152) {
    int pos = tid >> 6, c = tid & 63;
    ws[FEAT_OFF + tid] = f2bf(inp[c * 32768 + pos]);
  } else if (tid < W1F_OFF) {
    int e = tid - W0F_OFF;
    int j = e & 7, L = (e >> 3) & 63, nt = (e >> 9) & 15, c = e >> 13;
    int k = c * 32 + (L >> 4) * 8 + j, n = nt * 16 + (L & 15);
    ws[tid] = (k < 71) ? f2bf(W0[k * 256 + n]) : (unsigned short)0;
  } else if (tid < W2F_OFF) {
    int e = tid - W1F_OFF;
    int j = e & 7, L = (e >> 3) & 63, nt = (e >> 9) & 15, c = e >> 13;
    int kp = c * 32 + (L >> 4) * 8 + j, n = nt * 16 + (L & 15);
    ws[tid] = f2bf(W1[col_log(kp) * 256 + n]);
  } else if (tid < W3P_OFF) {
    int e = tid - W2F_OFF;
    int j = e & 7, L = (e >> 3) & 63, nt = (e >> 9) & 15, c = e >> 13;
    int kp = c * 32 + (L >> 4) * 8 + j, n = nt * 16 + (L & 15);
    ws[tid] = f2bf(W2[col_log(kp) * 256 + n]);
  } else if (tid < W3P_OFF + 256) {
    int e = tid - W3P_OFF;
    float* w3p = (float*)(ws + W3P_OFF);
    w3p[e] = W3[col_log(e)];
  }
}

// ---- MFMA half-layer: 64 rows x 256 cols over 4 waves (wave4 = col-group).
// Bias folded into acc init. If PRE, leaves next layer's c=0 B frags in flight.
template<int KC, bool PRE, bool SWZ>
__device__ __forceinline__ void layer_mfma(f32x4 (&acc)[4][4],
                                           const unsigned short* __restrict__ Wf,
                                           const float* __restrict__ bias,
                                           const unsigned short* A,
                                           const unsigned short* __restrict__ Wnext,
                                           s16x8 (&nb)[4],
                                           int wave4, int quad, int l16, int lane) {
#pragma unroll
  for (int ntl = 0; ntl < 4; ++ntl) {
    float bv = bias[(wave4 * 4 + ntl) * 16 + l16];
    f32x4 ai = (f32x4){bv, bv, bv, bv};
#pragma unroll
    for (int rt = 0; rt < 4; ++rt) acc[rt][ntl] = ai;
  }
  __builtin_amdgcn_s_setprio(1);
#pragma unroll
  for (int c = 0; c < KC; ++c) {
    s16x8 a[4];
#pragma unroll
    for (int rt = 0; rt < 4; ++rt) {
      int row = rt * 16 + l16, col = c * 32 + quad * 8;
      int idx = SWZ ? hswz(row, col) : row * 104 + col;
      a[rt] = *(const s16x8*)(A + idx);
    }
#pragma unroll
    for (int ntl = 0; ntl < 4; ++ntl) {
      s16x8 b = (c == 0) ? nb[ntl]
                         : *(const s16x8*)(Wf + (((c * 16 + wave4 * 4 + ntl) * 64 + lane) << 3));
#pragma unroll
      for (int rt = 0; rt < 4; ++rt)
        acc[rt][ntl] = __builtin_amdgcn_mfma_f32_16x16x32_bf16(a[rt], b, acc[rt][ntl], 0, 0, 0);
    }
  }
  __builtin_amdgcn_s_setprio(0);
  if constexpr (PRE) {
#pragma unroll
    for (int ntl = 0; ntl < 4; ++ntl)
      nb[ntl] = *(const s16x8*)(Wnext + (((wave4 * 4 + ntl) * 64 + lane) << 3));
  }
}

// ---- epilogue: relu + cvt_pk + swizzled b64 stores into tile H.
__device__ __forceinline__ void layer_epi(f32x4 (&acc)[4][4], unsigned short* H,
                                          int wave4, int quad, int l16) {
  const int cb = wave4 * 64 + l16 * 4;
#pragma unroll
  for (int rt = 0; rt < 4; ++rt) {
#pragma unroll
    for (int i = 0; i < 4; ++i) {
      float v0 = fmaxf(acc[rt][0][i], 0.0f);
      float v1 = fmaxf(acc[rt][1][i], 0.0f);
      float v2 = fmaxf(acc[rt][2][i], 0.0f);
      float v3 = fmaxf(acc[rt][3][i], 0.0f);
      int r = rt * 16 + quad * 4 + i;
      uint2 pw = make_uint2(cvt_pk_bf16(v0, v1), cvt_pk_bf16(v2, v3));
      *(uint2*)(H + hswz(r, cb)) = pw;
    }
  }
}

// ---- sampling for one 64-row tile, 256 threads (htid 0..255), 4/row.
__device__ __forceinline__ void sample_tile(const unsigned short* __restrict__ feat,
                                            const float* __restrict__ coord,
                                            const float* __restrict__ cell,
                                            unsigned short* T, int qbase,
                                            int htid, float& area) {
  const int row = htid >> 2, p = htid & 3;
  const int ql = row >> 3, s = row & 7;
  const int q = qbase + ql;
  const float c0r = coord[q * 3 + 0], c1r = coord[q * 3 + 1], c2r = coord[q * 3 + 2];
  const float R = 0.03125f;
  const float sh0 = ((s & 4) ? R : -R) + 1e-6f;
  const float sh1 = ((s & 2) ? R : -R) + 1e-6f;
  const float sh2 = ((s & 1) ? R : -R) + 1e-6f;
  const float LO = -1.0f + 1e-6f, HI = 1.0f - 1e-6f;
  float c0 = fminf(fmaxf(c0r + sh0, LO), HI);
  float c1 = fminf(fmaxf(c1r + sh1, LO), HI);
  float c2 = fminf(fmaxf(c2r + sh2, LO), HI);
  float z = (c0 + 1.0f) * 16.0f - 0.5f;
  float y = (c1 + 1.0f) * 16.0f - 0.5f;
  float x = (c2 + 1.0f) * 16.0f - 0.5f;
  float zf = floorf(z), yf = floorf(y), xf = floorf(x);
  float wz = z - zf, wy = y - yf, wx = x - xf;
  int z0 = min(max((int)zf, 0), 31), z1 = min(max((int)zf + 1, 0), 31);
  int y0 = min(max((int)yf, 0), 31), y1 = min(max((int)yf + 1, 0), 31);
  int x0 = min(max((int)xf, 0), 31), x1 = min(max((int)xf + 1, 0), 31);
  float wz0 = 1.0f - wz, wy0 = 1.0f - wy, wx0 = 1.0f - wx;

  float w[8] = { wz0 * wy0 * wx0, wz0 * wy0 * wx, wz0 * wy * wx0, wz0 * wy * wx,
                 wz  * wy0 * wx0, wz  * wy0 * wx, wz  * wy * wx0, wz  * wy * wx };
  int idx[8] = { (z0 * 32 + y0) * 32 + x0, (z0 * 32 + y0) * 32 + x1,
                 (z0 * 32 + y1) * 32 + x0, (z0 * 32 + y1) * 32 + x1,
                 (z1 * 32 + y0) * 32 + x0, (z1 * 32 + y0) * 32 + x1,
                 (z1 * 32 + y1) * 32 + x0, (z1 * 32 + y1) * 32 + x1 };

  float acc[16];
#pragma unroll
  for (int i = 0; i < 16; ++i) acc[i] = 0.0f;
#pragma unroll
  for (int corner = 0; corner < 8; ++corner) {
    const uint4* cp = (const uint4*)(feat + idx[corner] * 64 + p * 16);
    uint4 v0 = cp[0], v1 = cp[1];
    float wc = w[corner];
    unsigned vv[8] = { v0.x, v0.y, v0.z, v0.w, v1.x, v1.y, v1.z, v1.w };
#pragma unroll
    for (int d = 0; d < 8; ++d) {
      acc[2 * d]     += wc * bflo(vv[d]);
      acc[2 * d + 1] += wc * bfhi(vv[d]);
    }
  }
  unsigned pw[8];
#pragma unroll
  for (int d = 0; d < 8; ++d)
    pw[d] = cvt_pk_bf16(acc[2 * d], acc[2 * d + 1]);
  uint4* dst = (uint4*)(T + row * 104 + p * 16);
  dst[0] = make_uint4(pw[0], pw[1], pw[2], pw[3]);
  dst[1] = make_uint4(pw[4], pw[5], pw[6], pw[7]);

  if (p == 0) {
    const float step = 2.0f / 31.0f;
    float qc0 = wx0 * (-1.0f + step * x0) + wx * (-1.0f + step * x1);
    float qc1 = wy0 * (-1.0f + step * y0) + wy * (-1.0f + step * y1);
    float qc2 = wz0 * (-1.0f + step * z0) + wz * (-1.0f + step * z1);
    float rel0 = (c0r - qc0) * 32.0f;
    float rel1 = (c1r - qc1) * 32.0f;
    float rel2 = (c2r - qc2) * 32.0f;
    area = fabsf(rel0 * rel1 * rel2) + 1e-9f;
    float cl0 = cell[q * 3 + 0], cl1 = cell[q * 3 + 1], cl2 = cell[q * 3 + 2];
    float ssq = fminf(fmaxf(8.0f / (fabsf(cl0 * cl1 * cl2) + 1e-8f), 1.0f), 64.0f);
    unsigned tw0 = cvt_pk_bf16(rel0, rel1);
    unsigned tw1 = cvt_pk_bf16(rel2, cl0 * 32.0f);
    unsigned tw2 = cvt_pk_bf16(cl1 * 32.0f, cl2 * 32.0f);
    unsigned tw3 = cvt_pk_bf16(ssq, 0.0f);
    uint4* d2 = (uint4*)(T + row * 104 + 64);
    d2[0] = make_uint4(tw0, tw1, tw2, tw3);
    d2[1] = make_uint4(0, 0, 0, 0);  // cols 72..95 must be ZERO (K pad reads them)
    d2[2] = make_uint4(0, 0, 0, 0);
    d2[3] = make_uint4(0, 0, 0, 0);
  }
}

// ---- layer3 + shuffle combine + store (no LDS arrays, no barrier needed).
__device__ __forceinline__ void l3_combine(const unsigned short* T,
                                           const float* __restrict__ W3p,
                                           const float* __restrict__ b3,
                                           float area, float* __restrict__ out,
                                           int qbase, int htid, int lane) {
  const int row = htid >> 2, p = htid & 3;
  float sum = 0.0f;
#pragma unroll
  for (int kk = 0; kk < 8; ++kk) {
    int col = p * 64 + kk * 8;
    const uint4 v = *(const uint4*)(T + hswz(row, col));
    const float4 wa = *(const float4*)(W3p + col);
    const float4 wb = *(const float4*)(W3p + col + 4);
    sum += wa.x * bflo(v.x) + wa.y * bfhi(v.x);
    sum += wa.z * bflo(v.y) + wa.w * bfhi(v.y);
    sum += wb.x * bflo(v.z) + wb.y * bfhi(v.z);
    sum += wb.z * bflo(v.w) + wb.w * bfhi(v.w);
  }
  sum += __shfl_xor(sum, 1);
  sum += __shfl_xor(sum, 2);
  float pred = sum + b3[0];
  // the 8 shift-rows of this wave's queries live at lanes base+4s (p==0 lanes)
  const int base = lane & 32;
  float tot = 0.0f, ret = 0.0f;
#pragma unroll
  for (int s = 0; s < 8; ++s) {
    float as = __shfl(area, base + 4 * s, 64);
    float ar = __shfl(area, base + 4 * (7 - s), 64);  // areas reversed
    float ps = __shfl(pred, base + 4 * s, 64);
    tot += as;
    ret += ps * ar;
  }
  if ((lane & 31) == 0) {
    int ql = ((htid >> 6) << 1) + (lane >> 5);
    out[qbase + ql] = ret / tot;
  }
}

// 512 threads = 8 waves: waves 0-3 own tile A, waves 4-7 tile B, tile B's
// pipeline skewed one stage so MFMA phases overlap sampling/L3/VALU phases
// on the same SIMDs (anti-convoy). LDS = 2 x 64x256 bf16 = 65536 B
// (XOR-swizzled, no pad, area/pred via shuffles). Natural VGPR allocation
// (~128) + 64KB LDS -> 2 blocks/CU = 16 waves, same occupancy as r5.
__global__ __launch_bounds__(512)
void liif_main(const float* __restrict__ coord,
               const float* __restrict__ cell,
               const float* __restrict__ b0,
               const float* __restrict__ b1,
               const float* __restrict__ b2,
               const float* __restrict__ b3,
               const unsigned short* __restrict__ ws,
               float* __restrict__ out) {
  __shared__ __align__(16) unsigned short smA[64 * 256];
  __shared__ __align__(16) unsigned short smB[64 * 256];

  const unsigned short* feat = ws + FEAT_OFF;
  const float* W3p = (const float*)(ws + W3P_OFF);
  const int tid = threadIdx.x;
  const int lane = tid & 63;
  const int wave = tid >> 6;
  const int half = wave >> 2;   // 0: tile A, 1: tile B
  const int wave4 = wave & 3;   // col-group within the half
  const int quad = lane >> 4;
  const int l16 = lane & 15;
  const int htid = tid & 255;
  unsigned short* myT = half ? smB : smA;
  const int qb = blockIdx.x * 16;

  // both halves prefetch their W0 c=0 B frags at kernel start
  s16x8 nb[4];
#pragma unroll
  for (int ntl = 0; ntl < 4; ++ntl)
    nb[ntl] = *(const s16x8*)(ws + W0F_OFF + (((wave4 * 4 + ntl) * 64 + lane) << 3));

  float area = 0.0f;
  f32x4 acc[4][4];

  // P0: sample A                     (half1 idle)
  if (half == 0) sample_tile(feat, coord, cell, smA, qb, htid, area);
  lgkm_barrier();
  // P1: L0(A)-mfma  ||  sample B
  if (half == 0)
    layer_mfma<3, true, false>(acc, ws + W0F_OFF, b0, smA, ws + W1F_OFF, nb, wave4, quad, l16, lane);
  else
    sample_tile(feat, coord, cell, smB, qb + 8, htid, area);
  lgkm_barrier();
  if (half == 0) layer_epi(acc, smA, wave4, quad, l16);
  lgkm_barrier();
  // P2: L1(A)  ||  L0(B)
  if (half == 0)
    layer_mfma<8, true, true>(acc, ws + W1F_OFF, b1, smA, ws + W2F_OFF, nb, wave4, quad, l16, lane);
  else
    layer_mfma<3, true, false>(acc, ws + W0F_OFF, b0, smB, ws + W1F_OFF, nb, wave4, quad, l16, lane);
  lgkm_barrier();
  layer_epi(acc, myT, wave4, quad, l16);
  lgkm_barrier();
  // P3: L2(A)  ||  L1(B)
  if (half == 0)
    layer_mfma<8, false, true>(acc, ws + W2F_OFF, b2, smA, nullptr, nb, wave4, quad, l16, lane);
  else
    layer_mfma<8, true, true>(acc, ws + W1F_OFF, b1, smB, ws + W2F_OFF, nb, wave4, quad, l16, lane);
  lgkm_barrier();
  layer_epi(acc, myT, wave4, quad, l16);
  lgkm_barrier();
  // P4: L3+combine(A)  ||  L2(B)
  if (half == 0)
    l3_combine(smA, W3p, b3, area, out, qb, htid, lane);
  else
    layer_mfma<8, false, true>(acc, ws + W2F_OFF, b2, smB, nullptr, nb, wave4, quad, l16, lane);
  lgkm_barrier();
  if (half == 1) layer_epi(acc, smB, wave4, quad, l16);
  lgkm_barrier();
  // P5: L3+combine(B)                (half0 idle)
  if (half == 1)
    l3_combine(smB, W3p, b3, area, out, qb + 8, htid, lane);
}

extern "C" void kernel_launch(void* const* d_in, const int* in_sizes, int n_in,
                              void* d_out, int out_size, void* d_ws, size_t ws_size,
                              hipStream_t stream) {
  const float* inp   = (const float*)d_in[0];
  const float* coord = (const float*)d_in[1];
  const float* cell  = (const float*)d_in[2];
  const float* W0    = (const float*)d_in[3];
  const float* b0    = (const float*)d_in[4];
  const float* W1    = (const float*)d_in[5];
  const float* b1    = (const float*)d_in[6];
  const float* W2    = (const float*)d_in[7];
  const float* b2    = (const float*)d_in[8];
  const float* W3    = (const float*)d_in[9];
  const float* b3    = (const float*)d_in[10];
  unsigned short* ws = (unsigned short*)d_ws;
  float* out = (float*)d_out;

  const int Q = in_sizes[1] / 3;  // 131072
  hipLaunchKernelGGL(liif_prep, dim3((WS_TOTAL + 255) / 256), dim3(256), 0, stream,
                     inp, W0, W1, W2, W3, ws);
  hipLaunchKernelGGL(liif_main, dim3(Q / 16), dim3(512), 0, stream,
                     coord, cell, b0, b1, b2, b3, ws, out);
}